// Round 6
// baseline (939.201 us; speedup 1.0000x reference)
//
#include <hip/hip_runtime.h>
#include <hip/hip_bf16.h>

typedef float f32x4 __attribute__((ext_vector_type(4)));
typedef unsigned short u16x8 __attribute__((ext_vector_type(8)));

static __device__ __forceinline__ void mfma16(f32x4& c, const u16x8& a, const u16x8& b) {
    asm("v_mfma_f32_16x16x32_bf16 %0, %1, %2, %0" : "+v"(c) : "v"(a), "v"(b));
}

static __device__ __forceinline__ unsigned short f2bf(float f) {
    __hip_bfloat16 h = __float2bfloat16(f);
    return *reinterpret_cast<unsigned short*>(&h);
}

// ---------------- small prep kernels ----------------

__global__ __launch_bounds__(256) void k_dis(float* deg, int N) {
    int i = blockIdx.x * 256 + threadIdx.x;
    if (i >= N) return;
    float d = deg[i];
    deg[i] = (d > 0.f) ? rsqrtf(d) : 0.f;
}

__global__ __launch_bounds__(1024) void k_blocksum(const int* __restrict__ cnt, int* bsum, int N) {
    __shared__ int sd[1024];
    int i = blockIdx.x * 1024 + threadIdx.x;
    sd[threadIdx.x] = (i < N) ? cnt[i] : 0;
    __syncthreads();
    for (int s = 512; s > 0; s >>= 1) {
        if (threadIdx.x < s) sd[threadIdx.x] += sd[threadIdx.x + s];
        __syncthreads();
    }
    if (threadIdx.x == 0) bsum[blockIdx.x] = sd[0];
}

__global__ __launch_bounds__(128) void k_scan_bsum(int* bsum, int nb) {
    __shared__ int sd[128];
    int t = threadIdx.x;
    int v = (t < nb) ? bsum[t] : 0;
    sd[t] = v;
    __syncthreads();
    for (int d = 1; d < 128; d <<= 1) {
        int x = (t >= d) ? sd[t - d] : 0;
        __syncthreads();
        sd[t] += x;
        __syncthreads();
    }
    if (t < nb) bsum[t] = sd[t] - v;  // exclusive block offsets
}

__global__ __launch_bounds__(1024) void k_scan(const int* __restrict__ cnt, const int* __restrict__ bsum,
                                               int* rowp, int* cur, int N) {
    __shared__ int sd[1024];
    int i = blockIdx.x * 1024 + threadIdx.x;
    int v = (i < N) ? cnt[i] : 0;
    sd[threadIdx.x] = v;
    __syncthreads();
    for (int d = 1; d < 1024; d <<= 1) {
        int x = (threadIdx.x >= d) ? sd[threadIdx.x - d] : 0;
        __syncthreads();
        sd[threadIdx.x] += x;
        __syncthreads();
    }
    if (i < N) {
        int excl = sd[threadIdx.x] - v + bsum[blockIdx.x];
        rowp[i] = excl;
        cur[i]  = excl;
    }
}

// CSR fill via cursor atomics (returns position)
__global__ __launch_bounds__(256) void k_build_csr(const int* __restrict__ src, const int* __restrict__ dst,
                                                   const float* __restrict__ ew, const float* __restrict__ dis,
                                                   int* cur, int2* __restrict__ pack, int E) {
    int e = blockIdx.x * 256 + threadIdx.x;
    if (e >= E) return;
    int s = src[e], d = dst[e];
    float w = (s == d) ? 0.f : ew[e];
    float wh = -dis[s] * w * dis[d];
    int pos = atomicAdd(&cur[d], 1);
    int2 p;
    p.x = s;
    p.y = __float_as_int(wh);
    pack[pos] = p;
}

// ---------------- weight prep ----------------

// AT[sel][n][kk] = A_sel[kk][n] (transposed, bf16), A0=W0-W2, A1=W1-3W3, A2=2W2, A3=4W3
__global__ __launch_bounds__(256) void k_combine(const float* __restrict__ W, unsigned short* __restrict__ AT,
                                                 int D, int KPAD) {
    int i = blockIdx.x * 256 + threadIdx.x;
    int tot = 4 * 128 * KPAD;
    if (i >= tot) return;
    int sel = i / (128 * KPAD);
    int rem = i - sel * 128 * KPAD;
    int n = rem / KPAD;
    int kk = rem - n * KPAD;
    float v = 0.f;
    if (kk < D) {
        if (sel == 0)      v = W[(0 * D + kk) * 128 + n] - W[(2 * D + kk) * 128 + n];
        else if (sel == 1) v = W[(1 * D + kk) * 128 + n] - 3.f * W[(3 * D + kk) * 128 + n];
        else if (sel == 2) v = 2.f * W[(2 * D + kk) * 128 + n];
        else               v = 4.f * W[(3 * D + kk) * 128 + n];
    }
    AT[i] = f2bf(v);
}

__global__ __launch_bounds__(256) void k_headsT(const float* __restrict__ Wmu, const float* __restrict__ Wlv,
                                                unsigned short* __restrict__ AT) {
    int i = blockIdx.x * 256 + threadIdx.x;
    if (i >= 128 * 128) return;
    int n = i >> 7, kk = i & 127;
    float v = (n < 64) ? Wmu[kk * 64 + n] : Wlv[kk * 64 + (n - 64)];
    AT[i] = f2bf(v);
}

// ---------------- reg-B pair GEMM body: BM=64, BN=128 (all cols), 2 weights/block ----------------
// A staged in LDS (LP=KPAD+8); B fragments loaded global->VGPR (weights are L2-resident).
// wave roles: wm=wave&1 (row half), ww=wave>>1 (weight select).

template <int KPAD, int SRC>
static __device__ __forceinline__ void gemm_pair_regB(const unsigned short* __restrict__ Abf,
                                                      const float* __restrict__ x,
                                                      const float* __restrict__ pe,
                                                      const unsigned short* __restrict__ Bta,
                                                      const unsigned short* __restrict__ Btb,
                                                      unsigned short* __restrict__ outA,
                                                      unsigned short* __restrict__ outB,
                                                      int N, int bx, unsigned short* As) {
    constexpr int LP = KPAD + 8;
    const int tid = threadIdx.x;
    const int row0 = bx * 64;

    {   // stage A tile (64 x KPAD)
        constexpr int TOT = 64 * KPAD;
        for (int c = tid * 8; c < TOT; c += 256 * 8) {
            int r = c / KPAD;
            int k = c - r * KPAD;
            int gr = row0 + r;
            if (gr > N - 1) gr = N - 1;
            u16x8 v;
            if (SRC == 0) {
                v = *reinterpret_cast<const u16x8*>(&Abf[(size_t)gr * KPAD + k]);
            } else {
                if (k < 128) {
                    float4 f0 = *reinterpret_cast<const float4*>(&x[(size_t)gr * 128 + k]);
                    float4 f1 = *reinterpret_cast<const float4*>(&x[(size_t)gr * 128 + k + 4]);
                    v[0] = f2bf(f0.x); v[1] = f2bf(f0.y); v[2] = f2bf(f0.z); v[3] = f2bf(f0.w);
                    v[4] = f2bf(f1.x); v[5] = f2bf(f1.y); v[6] = f2bf(f1.z); v[7] = f2bf(f1.w);
                } else if (k < 144) {
                    float4 f0 = *reinterpret_cast<const float4*>(&pe[(size_t)gr * 16 + (k - 128)]);
                    float4 f1 = *reinterpret_cast<const float4*>(&pe[(size_t)gr * 16 + (k - 124)]);
                    v[0] = f2bf(f0.x); v[1] = f2bf(f0.y); v[2] = f2bf(f0.z); v[3] = f2bf(f0.w);
                    v[4] = f2bf(f1.x); v[5] = f2bf(f1.y); v[6] = f2bf(f1.z); v[7] = f2bf(f1.w);
                } else {
                    v = (u16x8){0, 0, 0, 0, 0, 0, 0, 0};
                }
            }
            *reinterpret_cast<u16x8*>(&As[r * LP + k]) = v;
        }
    }
    __syncthreads();

    const int wave = tid >> 6, lane = tid & 63;
    const int wm = wave & 1, ww = wave >> 1;
    const int lr = lane & 15, lg = lane >> 4;
    const unsigned short* Bw = ww ? Btb : Bta;

    f32x4 acc[2][8];
#pragma unroll
    for (int i = 0; i < 2; i++)
#pragma unroll
        for (int j = 0; j < 8; j++) acc[i][j] = (f32x4){0.f, 0.f, 0.f, 0.f};

    asm volatile("s_nop 7"
                 : "+v"(acc[0][0]), "+v"(acc[0][4]), "+v"(acc[1][0]), "+v"(acc[1][4]));

    constexpr int KS = KPAD / 32;
#pragma unroll
    for (int ks = 0; ks < KS; ks++) {
        u16x8 a0 = *reinterpret_cast<const u16x8*>(&As[(wm * 32 + lr) * LP + ks * 32 + lg * 8]);
        u16x8 a1 = *reinterpret_cast<const u16x8*>(&As[(wm * 32 + 16 + lr) * LP + ks * 32 + lg * 8]);
#pragma unroll
        for (int g = 0; g < 2; g++) {
            u16x8 b[4];
#pragma unroll
            for (int j = 0; j < 4; j++)
                b[j] = *reinterpret_cast<const u16x8*>(&Bw[(size_t)((g * 4 + j) * 16 + lr) * KPAD + ks * 32 + lg * 8]);
#pragma unroll
            for (int j = 0; j < 4; j++) {
                mfma16(acc[0][g * 4 + j], a0, b[j]);
                mfma16(acc[1][g * 4 + j], a1, b[j]);
            }
        }
    }

    asm volatile("s_nop 7\n\ts_nop 7\n\ts_nop 7"
                 : "+v"(acc[0][0]), "+v"(acc[0][4]), "+v"(acc[1][0]), "+v"(acc[1][4]));

    unsigned short* outp = ww ? outB : outA;
#pragma unroll
    for (int fm = 0; fm < 2; fm++)
#pragma unroll
        for (int fn = 0; fn < 8; fn++)
#pragma unroll
            for (int i = 0; i < 4; i++) {
                int r = row0 + wm * 32 + fm * 16 + lg * 4 + i;
                if (r < N) outp[(size_t)r * 128 + fn * 16 + lr] = f2bf(acc[fm][fn][i]);
            }
}

// layer-1: grid = (G64, 2); y picks pair P.
__global__ __launch_bounds__(256, 4) void k_gemm_pair128(const unsigned short* __restrict__ Abf,
                                                         const unsigned short* __restrict__ AT1,
                                                         unsigned short* __restrict__ oZ3,
                                                         unsigned short* __restrict__ oZ2,
                                                         unsigned short* __restrict__ oZ1,
                                                         unsigned short* __restrict__ oZ0,
                                                         int N) {
    __shared__ __align__(16) unsigned short As[64 * 136];
    const int P = blockIdx.y;
    const unsigned short* Bta = AT1 + (size_t)(3 - 2 * P) * 128 * 128;
    const unsigned short* Btb = AT1 + (size_t)(2 - 2 * P) * 128 * 128;
    unsigned short* outA = (P == 0) ? oZ3 : oZ1;
    unsigned short* outB = (P == 0) ? oZ2 : oZ0;
    gemm_pair_regB<128, 0>(Abf, nullptr, nullptr, Bta, Btb, outA, outB, N, blockIdx.x, As);
}

// ---------------- K1 mega: {layer-0 pair-GEMM tile} then {fire-and-forget deg/cnt atomics} ----------------

__global__ __launch_bounds__(256, 4) void k_mega(const int* __restrict__ src, const int* __restrict__ dst,
                                                 const float* __restrict__ ew,
                                                 float* deg, int* cnt,
                                                 const float* __restrict__ x, const float* __restrict__ pe,
                                                 const unsigned short* __restrict__ AT0,
                                                 unsigned short* __restrict__ oZ3, unsigned short* __restrict__ oZ2,
                                                 unsigned short* __restrict__ oZ1, unsigned short* __restrict__ oZ0,
                                                 int N, int E, int EPC) {
    __shared__ __align__(16) unsigned short As[64 * 168];
    const int bid = blockIdx.x;

    // phase 1: layer-0 pair GEMM tile (fused concat from f32 x|pe); P interleaved for A-row L2 reuse
    {
        int P = bid & 1;
        int bx = bid >> 1;
        const unsigned short* Bta = AT0 + (size_t)(3 - 2 * P) * 128 * 160;
        const unsigned short* Btb = AT0 + (size_t)(2 - 2 * P) * 128 * 160;
        unsigned short* outA = (P == 0) ? oZ3 : oZ1;
        unsigned short* outB = (P == 0) ? oZ2 : oZ0;
        gemm_pair_regB<160, 1>(nullptr, x, pe, Bta, Btb, outA, outB, N, bx, As);
    }

    // phase 2: fire-and-forget atomics (no returns -> no waits; endpgm doesn't drain stores)
    {
        int e0 = bid * EPC;
        int e1 = e0 + EPC;
        if (e1 > E) e1 = E;
        for (int e = e0 + threadIdx.x; e < e1; e += 256) {
            int s = src[e], d = dst[e];
            float w = (s == d) ? 0.f : ew[e];
            atomicAdd(&deg[s], w);
            atomicAdd(&cnt[d], 1);
        }
    }
}

// ---------------- heads GEMM: BM=128, reg-B; [mu|logvar](f32) + bias ----------------

__global__ __launch_bounds__(256, 4) void k_gemm_heads(const unsigned short* __restrict__ Abf,
                                                       const unsigned short* __restrict__ Bt,
                                                       float* __restrict__ out,
                                                       const float* __restrict__ bmu, const float* __restrict__ blv,
                                                       int N) {
    constexpr int KPAD = 128;
    constexpr int LP = KPAD + 8;
    __shared__ __align__(16) unsigned short As[128 * LP];
    const int tid = threadIdx.x;
    const int row0 = blockIdx.x * 128;

    {
        constexpr int TOT = 128 * KPAD;
        for (int c = tid * 8; c < TOT; c += 256 * 8) {
            int r = c / KPAD;
            int k = c - r * KPAD;
            int gr = row0 + r;
            if (gr > N - 1) gr = N - 1;
            u16x8 v = *reinterpret_cast<const u16x8*>(&Abf[(size_t)gr * KPAD + k]);
            *reinterpret_cast<u16x8*>(&As[r * LP + k]) = v;
        }
    }
    __syncthreads();

    const int wave = tid >> 6, lane = tid & 63;
    const int lr = lane & 15, lg = lane >> 4;

    f32x4 acc[2][8];
#pragma unroll
    for (int i = 0; i < 2; i++)
#pragma unroll
        for (int j = 0; j < 8; j++) acc[i][j] = (f32x4){0.f, 0.f, 0.f, 0.f};

    asm volatile("s_nop 7"
                 : "+v"(acc[0][0]), "+v"(acc[0][4]), "+v"(acc[1][0]), "+v"(acc[1][4]));

#pragma unroll
    for (int ks = 0; ks < KPAD / 32; ks++) {
        u16x8 a0 = *reinterpret_cast<const u16x8*>(&As[(wave * 32 + lr) * LP + ks * 32 + lg * 8]);
        u16x8 a1 = *reinterpret_cast<const u16x8*>(&As[(wave * 32 + 16 + lr) * LP + ks * 32 + lg * 8]);
#pragma unroll
        for (int g = 0; g < 2; g++) {
            u16x8 b[4];
#pragma unroll
            for (int j = 0; j < 4; j++)
                b[j] = *reinterpret_cast<const u16x8*>(&Bt[(size_t)((g * 4 + j) * 16 + lr) * KPAD + ks * 32 + lg * 8]);
#pragma unroll
            for (int j = 0; j < 4; j++) {
                mfma16(acc[0][g * 4 + j], a0, b[j]);
                mfma16(acc[1][g * 4 + j], a1, b[j]);
            }
        }
    }

    asm volatile("s_nop 7\n\ts_nop 7\n\ts_nop 7"
                 : "+v"(acc[0][0]), "+v"(acc[0][4]), "+v"(acc[1][0]), "+v"(acc[1][4]));

#pragma unroll
    for (int fm = 0; fm < 2; fm++)
#pragma unroll
        for (int fn = 0; fn < 8; fn++)
#pragma unroll
            for (int i = 0; i < 4; i++) {
                int r = row0 + wave * 32 + fm * 16 + lg * 4 + i;
                if (r < N) {
                    int c = fn * 16 + lr;
                    if (c < 64) out[(size_t)r * 64 + c] = acc[fm][fn][i] + bmu[c];
                    else out[(size_t)N * 64 + (size_t)r * 64 + (c - 64)] = acc[fm][fn][i] + blv[c - 64];
                }
            }
}

// ---------------- sparse prop: tout = [relu](z + P*tin [+ bias])  — all bf16, fp32 accum ----------------

template <int MODE>  // 0: plain ; 1: + bias, relu
__global__ __launch_bounds__(256) void k_prop(const unsigned int* __restrict__ tin,
                                              const unsigned int* __restrict__ z,
                                              unsigned int* __restrict__ tout,
                                              const float* __restrict__ bias,
                                              const int* __restrict__ rowp,
                                              const long long* __restrict__ pack,
                                              int N, int E) {
    int wave = threadIdx.x >> 6, lane = threadIdx.x & 63;
    int node = blockIdx.x * 4 + wave;
    if (node >= N) return;
    int beg = rowp[node];
    int end = (node == N - 1) ? E : rowp[node + 1];
    float ax = 0.f, ay = 0.f;
    int e = beg;
    for (; e + 3 < end; e += 4) {
        long long q0 = __builtin_nontemporal_load(pack + e);
        long long q1 = __builtin_nontemporal_load(pack + e + 1);
        long long q2 = __builtin_nontemporal_load(pack + e + 2);
        long long q3 = __builtin_nontemporal_load(pack + e + 3);
        unsigned int v0 = tin[(size_t)(unsigned int)q0 * 64 + lane];
        unsigned int v1 = tin[(size_t)(unsigned int)q1 * 64 + lane];
        unsigned int v2 = tin[(size_t)(unsigned int)q2 * 64 + lane];
        unsigned int v3 = tin[(size_t)(unsigned int)q3 * 64 + lane];
        float w0 = __uint_as_float((unsigned int)((unsigned long long)q0 >> 32));
        float w1 = __uint_as_float((unsigned int)((unsigned long long)q1 >> 32));
        float w2 = __uint_as_float((unsigned int)((unsigned long long)q2 >> 32));
        float w3 = __uint_as_float((unsigned int)((unsigned long long)q3 >> 32));
        ax = fmaf(w0, __uint_as_float(v0 << 16), ax);
        ay = fmaf(w0, __uint_as_float(v0 & 0xffff0000u), ay);
        ax = fmaf(w1, __uint_as_float(v1 << 16), ax);
        ay = fmaf(w1, __uint_as_float(v1 & 0xffff0000u), ay);
        ax = fmaf(w2, __uint_as_float(v2 << 16), ax);
        ay = fmaf(w2, __uint_as_float(v2 & 0xffff0000u), ay);
        ax = fmaf(w3, __uint_as_float(v3 << 16), ax);
        ay = fmaf(w3, __uint_as_float(v3 & 0xffff0000u), ay);
    }
    for (; e < end; e++) {
        long long q0 = __builtin_nontemporal_load(pack + e);
        unsigned int v0 = tin[(size_t)(unsigned int)q0 * 64 + lane];
        float w0 = __uint_as_float((unsigned int)((unsigned long long)q0 >> 32));
        ax = fmaf(w0, __uint_as_float(v0 << 16), ax);
        ay = fmaf(w0, __uint_as_float(v0 & 0xffff0000u), ay);
    }
    unsigned int zv = __builtin_nontemporal_load(z + (size_t)node * 64 + lane);
    float rx = __uint_as_float(zv << 16) + ax;
    float ry = __uint_as_float(zv & 0xffff0000u) + ay;
    if (MODE == 1) {
        rx = fmaxf(rx + bias[lane * 2], 0.f);
        ry = fmaxf(ry + bias[lane * 2 + 1], 0.f);
    }
    unsigned int lo = f2bf(rx), hi = f2bf(ry);
    tout[(size_t)node * 64 + lane] = lo | (hi << 16);
}

// ---------------- launch ----------------

extern "C" void kernel_launch(void* const* d_in, const int* in_sizes, int n_in,
                              void* d_out, int out_size, void* d_ws, size_t ws_size,
                              hipStream_t stream) {
    const float* x   = (const float*)d_in[0];
    const int*   ei  = (const int*)d_in[1];
    const float* pe  = (const float*)d_in[2];
    const float* ew  = (const float*)d_in[3];
    const float* W0  = (const float*)d_in[4];
    const float* b0  = (const float*)d_in[5];
    const float* W1  = (const float*)d_in[6];
    const float* b1  = (const float*)d_in[7];
    const float* Wmu = (const float*)d_in[8];
    const float* bmu = (const float*)d_in[9];
    const float* Wlv = (const float*)d_in[10];
    const float* blv = (const float*)d_in[11];

    const int N = in_sizes[0] / 128;
    const int E = in_sizes[3];
    const int* src = ei;
    const int* dst = ei + E;

    char* ws = (char*)d_ws;
    size_t off = 0;
    auto alloc = [&](size_t bytes) {
        size_t o = off;
        off += (bytes + 1023) & ~(size_t)1023;
        return o;
    };
    float* deg = (float*)(ws + alloc(4 * (size_t)N));   // becomes dis in-place
    int* cnt   = (int*)(ws + alloc(4 * (size_t)N));
    size_t zero_bytes = off;                            // memset deg+cnt
    int* cur   = (int*)(ws + alloc(4 * (size_t)N));
    int* rowp  = (int*)(ws + alloc(4 * (size_t)N));
    int* bsum  = (int*)(ws + alloc(4 * 128));
    unsigned short* AT0 = (unsigned short*)(ws + alloc(2 * 4 * 128 * 160));
    unsigned short* AT1 = (unsigned short*)(ws + alloc(2 * 4 * 128 * 128));
    unsigned short* ATH = (unsigned short*)(ws + alloc(2 * 128 * 128));
    int2* pack = (int2*)(ws + alloc(8 * (size_t)E));
    unsigned int* B1 = (unsigned int*)(ws + alloc(2 * (size_t)N * 128));
    unsigned int* B2 = (unsigned int*)(ws + alloc(2 * (size_t)N * 128));
    unsigned int* B3 = (unsigned int*)(ws + alloc(2 * (size_t)N * 128));
    unsigned int* B4 = (unsigned int*)(ws + alloc(2 * (size_t)N * 128));
    unsigned int* B5 = (unsigned int*)(ws + alloc(2 * (size_t)N * 128));

    hipMemsetAsync(ws, 0, zero_bytes, stream);

    dim3 b256(256);
    // weight prep (mega's gemm blocks read AT0)
    k_combine<<<dim3((4 * 128 * 160 + 255) / 256), b256, 0, stream>>>(W0, AT0, 144, 160);
    k_combine<<<dim3((4 * 128 * 128 + 255) / 256), b256, 0, stream>>>(W1, AT1, 128, 128);
    k_headsT<<<dim3((128 * 128 + 255) / 256), b256, 0, stream>>>(Wmu, Wlv, ATH);

    // K1: every block = layer-0 pair-GEMM tile (fused concat), then fire-and-forget atomics
    int G64 = (N + 63) / 64;
    int total = 2 * G64;
    int EPC = (E + total - 1) / total;
    k_mega<<<dim3(total), b256, 0, stream>>>(src, dst, ew, deg, cnt, x, pe, AT0,
                                             (unsigned short*)B1, (unsigned short*)B2,
                                             (unsigned short*)B3, (unsigned short*)B4,
                                             N, E, EPC);

    k_dis<<<dim3((N + 255) / 256), b256, 0, stream>>>(deg, N);
    int nb = (N + 1023) / 1024;
    k_blocksum<<<dim3(nb), dim3(1024), 0, stream>>>(cnt, bsum, N);
    k_scan_bsum<<<dim3(1), dim3(128), 0, stream>>>(bsum, nb);
    k_scan<<<dim3(nb), dim3(1024), 0, stream>>>(cnt, bsum, rowp, cur, N);
    k_build_csr<<<dim3((E + 255) / 256), b256, 0, stream>>>(src, dst, ew, deg, cur, pack, E);

    dim3 gg(G64, 2);
    dim3 gh((N + 127) / 128);
    dim3 gp((N + 3) / 4);
    const long long* packll = (const long long*)pack;

    // layer 0 (Horner): B1=Z3 B2=Z2 B3=Z1 B4=Z0 (from K1)
    k_prop<0><<<gp, b256, 0, stream>>>(B1, B2, B5, nullptr, rowp, packll, N, E);   // B5 = Z2 + P Z3
    k_prop<0><<<gp, b256, 0, stream>>>(B5, B3, B1, nullptr, rowp, packll, N, E);   // B1 = Z1 + P B5
    k_prop<1><<<gp, b256, 0, stream>>>(B1, B4, B2, b0, rowp, packll, N, E);        // B2 = h1

    // layer 1: both pairs in one launch
    const unsigned short* h1 = (const unsigned short*)B2;
    k_gemm_pair128<<<gg, b256, 0, stream>>>(h1, AT1,
                                            (unsigned short*)B3, (unsigned short*)B4,
                                            (unsigned short*)B1, (unsigned short*)B5, N);
    k_prop<0><<<gp, b256, 0, stream>>>(B3, B4, B2, nullptr, rowp, packll, N, E);   // B2 = Z2' + P Z3'
    k_prop<0><<<gp, b256, 0, stream>>>(B2, B1, B3, nullptr, rowp, packll, N, E);   // B3 = Z1' + P B2
    k_prop<1><<<gp, b256, 0, stream>>>(B3, B5, B4, b1, rowp, packll, N, E);        // B4 = h2

    // heads
    k_gemm_heads<<<gh, b256, 0, stream>>>((const unsigned short*)B4, ATH, (float*)d_out, bmu, blv, N);
}

// Round 7
// 842.405 us; speedup vs baseline: 1.1149x; 1.1149x over previous
//
#include <hip/hip_runtime.h>
#include <hip/hip_bf16.h>

typedef float f32x4 __attribute__((ext_vector_type(4)));
typedef unsigned short u16x8 __attribute__((ext_vector_type(8)));

static __device__ __forceinline__ void mfma16(f32x4& c, const u16x8& a, const u16x8& b) {
    asm("v_mfma_f32_16x16x32_bf16 %0, %1, %2, %0" : "+v"(c) : "v"(a), "v"(b));
}

static __device__ __forceinline__ unsigned short f2bf(float f) {
    __hip_bfloat16 h = __float2bfloat16(f);
    return *reinterpret_cast<unsigned short*>(&h);
}

static __device__ __forceinline__ float bflo(unsigned int v) { return __uint_as_float(v << 16); }
static __device__ __forceinline__ float bfhi(unsigned int v) { return __uint_as_float(v & 0xffff0000u); }

// ---------------- small prep kernels ----------------

__global__ __launch_bounds__(256) void k_dis(float* deg, int N) {
    int i = blockIdx.x * 256 + threadIdx.x;
    if (i >= N) return;
    float d = deg[i];
    deg[i] = (d > 0.f) ? rsqrtf(d) : 0.f;
}

__global__ __launch_bounds__(1024) void k_blocksum(const int* __restrict__ cnt, int* bsum, int N) {
    __shared__ int sd[1024];
    int i = blockIdx.x * 1024 + threadIdx.x;
    sd[threadIdx.x] = (i < N) ? cnt[i] : 0;
    __syncthreads();
    for (int s = 512; s > 0; s >>= 1) {
        if (threadIdx.x < s) sd[threadIdx.x] += sd[threadIdx.x + s];
        __syncthreads();
    }
    if (threadIdx.x == 0) bsum[blockIdx.x] = sd[0];
}

__global__ __launch_bounds__(128) void k_scan_bsum(int* bsum, int nb) {
    __shared__ int sd[128];
    int t = threadIdx.x;
    int v = (t < nb) ? bsum[t] : 0;
    sd[t] = v;
    __syncthreads();
    for (int d = 1; d < 128; d <<= 1) {
        int x = (t >= d) ? sd[t - d] : 0;
        __syncthreads();
        sd[t] += x;
        __syncthreads();
    }
    if (t < nb) bsum[t] = sd[t] - v;  // exclusive block offsets
}

__global__ __launch_bounds__(1024) void k_scan(const int* __restrict__ cnt, const int* __restrict__ bsum,
                                               int* rowp, int N) {
    __shared__ int sd[1024];
    int i = blockIdx.x * 1024 + threadIdx.x;
    int v = (i < N) ? cnt[i] : 0;
    sd[threadIdx.x] = v;
    __syncthreads();
    for (int d = 1; d < 1024; d <<= 1) {
        int x = (threadIdx.x >= d) ? sd[threadIdx.x - d] : 0;
        __syncthreads();
        sd[threadIdx.x] += x;
        __syncthreads();
    }
    if (i < N) rowp[i] = sd[threadIdx.x] - v + bsum[blockIdx.x];
}

// atomic-free CSR fill: pos = rowp[dst] + rank (u8, captured during mega's counting atomics)
__global__ __launch_bounds__(256) void k_build_csr(const int* __restrict__ src, const int* __restrict__ dst,
                                                   const float* __restrict__ ew, const float* __restrict__ dis,
                                                   const int* __restrict__ rowp,
                                                   const unsigned char* __restrict__ rank,
                                                   int2* __restrict__ pack, int E) {
    int base = blockIdx.x * 512 + threadIdx.x;
#pragma unroll
    for (int u = 0; u < 2; u++) {
        int e = base + u * 256;
        if (e < E) {
            int s = src[e], d = dst[e];
            float w = (s == d) ? 0.f : ew[e];
            float wh = -dis[s] * w * dis[d];
            int pos = rowp[d] + (int)rank[e];
            int2 p;
            p.x = s;
            p.y = __float_as_int(wh);
            pack[pos] = p;
        }
    }
}

// ---------------- weight prep ----------------

// AT[sel][n][kk] = A_sel[kk][n] (transposed, bf16), A0=W0-W2, A1=W1-3W3, A2=2W2, A3=4W3
__global__ __launch_bounds__(256) void k_combine(const float* __restrict__ W, unsigned short* __restrict__ AT,
                                                 int D, int KPAD) {
    int i = blockIdx.x * 256 + threadIdx.x;
    int tot = 4 * 128 * KPAD;
    if (i >= tot) return;
    int sel = i / (128 * KPAD);
    int rem = i - sel * 128 * KPAD;
    int n = rem / KPAD;
    int kk = rem - n * KPAD;
    float v = 0.f;
    if (kk < D) {
        if (sel == 0)      v = W[(0 * D + kk) * 128 + n] - W[(2 * D + kk) * 128 + n];
        else if (sel == 1) v = W[(1 * D + kk) * 128 + n] - 3.f * W[(3 * D + kk) * 128 + n];
        else if (sel == 2) v = 2.f * W[(2 * D + kk) * 128 + n];
        else               v = 4.f * W[(3 * D + kk) * 128 + n];
    }
    AT[i] = f2bf(v);
}

__global__ __launch_bounds__(256) void k_headsT(const float* __restrict__ Wmu, const float* __restrict__ Wlv,
                                                unsigned short* __restrict__ AT) {
    int i = blockIdx.x * 256 + threadIdx.x;
    if (i >= 128 * 128) return;
    int n = i >> 7, kk = i & 127;
    float v = (n < 64) ? Wmu[kk * 64 + n] : Wlv[kk * 64 + (n - 64)];
    AT[i] = f2bf(v);
}

// ---------------- reg-B pair GEMM body: BM=64, BN=128 (all cols), 2 weights/block ----------------

template <int KPAD, int SRC>
static __device__ __forceinline__ void gemm_pair_regB(const unsigned short* __restrict__ Abf,
                                                      const float* __restrict__ x,
                                                      const float* __restrict__ pe,
                                                      const unsigned short* __restrict__ Bta,
                                                      const unsigned short* __restrict__ Btb,
                                                      unsigned short* __restrict__ outA,
                                                      unsigned short* __restrict__ outB,
                                                      int N, int bx, unsigned short* As) {
    constexpr int LP = KPAD + 8;
    const int tid = threadIdx.x;
    const int row0 = bx * 64;

    {   // stage A tile (64 x KPAD)
        constexpr int TOT = 64 * KPAD;
        for (int c = tid * 8; c < TOT; c += 256 * 8) {
            int r = c / KPAD;
            int k = c - r * KPAD;
            int gr = row0 + r;
            if (gr > N - 1) gr = N - 1;
            u16x8 v;
            if (SRC == 0) {
                v = *reinterpret_cast<const u16x8*>(&Abf[(size_t)gr * KPAD + k]);
            } else {
                if (k < 128) {
                    float4 f0 = *reinterpret_cast<const float4*>(&x[(size_t)gr * 128 + k]);
                    float4 f1 = *reinterpret_cast<const float4*>(&x[(size_t)gr * 128 + k + 4]);
                    v[0] = f2bf(f0.x); v[1] = f2bf(f0.y); v[2] = f2bf(f0.z); v[3] = f2bf(f0.w);
                    v[4] = f2bf(f1.x); v[5] = f2bf(f1.y); v[6] = f2bf(f1.z); v[7] = f2bf(f1.w);
                } else if (k < 144) {
                    float4 f0 = *reinterpret_cast<const float4*>(&pe[(size_t)gr * 16 + (k - 128)]);
                    float4 f1 = *reinterpret_cast<const float4*>(&pe[(size_t)gr * 16 + (k - 124)]);
                    v[0] = f2bf(f0.x); v[1] = f2bf(f0.y); v[2] = f2bf(f0.z); v[3] = f2bf(f0.w);
                    v[4] = f2bf(f1.x); v[5] = f2bf(f1.y); v[6] = f2bf(f1.z); v[7] = f2bf(f1.w);
                } else {
                    v = (u16x8){0, 0, 0, 0, 0, 0, 0, 0};
                }
            }
            *reinterpret_cast<u16x8*>(&As[r * LP + k]) = v;
        }
    }
    __syncthreads();

    const int wave = tid >> 6, lane = tid & 63;
    const int wm = wave & 1, ww = wave >> 1;
    const int lr = lane & 15, lg = lane >> 4;
    const unsigned short* Bw = ww ? Btb : Bta;

    f32x4 acc[2][8];
#pragma unroll
    for (int i = 0; i < 2; i++)
#pragma unroll
        for (int j = 0; j < 8; j++) acc[i][j] = (f32x4){0.f, 0.f, 0.f, 0.f};

    asm volatile("s_nop 7"
                 : "+v"(acc[0][0]), "+v"(acc[0][4]), "+v"(acc[1][0]), "+v"(acc[1][4]));

    constexpr int KS = KPAD / 32;
#pragma unroll
    for (int ks = 0; ks < KS; ks++) {
        u16x8 a0 = *reinterpret_cast<const u16x8*>(&As[(wm * 32 + lr) * LP + ks * 32 + lg * 8]);
        u16x8 a1 = *reinterpret_cast<const u16x8*>(&As[(wm * 32 + 16 + lr) * LP + ks * 32 + lg * 8]);
#pragma unroll
        for (int g = 0; g < 2; g++) {
            u16x8 b[4];
#pragma unroll
            for (int j = 0; j < 4; j++)
                b[j] = *reinterpret_cast<const u16x8*>(&Bw[(size_t)((g * 4 + j) * 16 + lr) * KPAD + ks * 32 + lg * 8]);
#pragma unroll
            for (int j = 0; j < 4; j++) {
                mfma16(acc[0][g * 4 + j], a0, b[j]);
                mfma16(acc[1][g * 4 + j], a1, b[j]);
            }
        }
    }

    asm volatile("s_nop 7\n\ts_nop 7\n\ts_nop 7"
                 : "+v"(acc[0][0]), "+v"(acc[0][4]), "+v"(acc[1][0]), "+v"(acc[1][4]));

    unsigned short* outp = ww ? outB : outA;
#pragma unroll
    for (int fm = 0; fm < 2; fm++)
#pragma unroll
        for (int fn = 0; fn < 8; fn++)
#pragma unroll
            for (int i = 0; i < 4; i++) {
                int r = row0 + wm * 32 + fm * 16 + lg * 4 + i;
                if (r < N) outp[(size_t)r * 128 + fn * 16 + lr] = f2bf(acc[fm][fn][i]);
            }
}

// layer-1: grid = (G64, 2); y picks pair P.
__global__ __launch_bounds__(256, 4) void k_gemm_pair128(const unsigned short* __restrict__ Abf,
                                                         const unsigned short* __restrict__ AT1,
                                                         unsigned short* __restrict__ oZ3,
                                                         unsigned short* __restrict__ oZ2,
                                                         unsigned short* __restrict__ oZ1,
                                                         unsigned short* __restrict__ oZ0,
                                                         int N) {
    __shared__ __align__(16) unsigned short As[64 * 136];
    const int P = blockIdx.y;
    const unsigned short* Bta = AT1 + (size_t)(3 - 2 * P) * 128 * 128;
    const unsigned short* Btb = AT1 + (size_t)(2 - 2 * P) * 128 * 128;
    unsigned short* outA = (P == 0) ? oZ3 : oZ1;
    unsigned short* outB = (P == 0) ? oZ2 : oZ0;
    gemm_pair_regB<128, 0>(Abf, nullptr, nullptr, Bta, Btb, outA, outB, N, blockIdx.x, As);
}

// ---------------- K1 mega: {layer-0 pair-GEMM tile} then {deg fire-and-forget + cnt/rank atomics} ----------------

__global__ __launch_bounds__(256, 4) void k_mega(const int* __restrict__ src, const int* __restrict__ dst,
                                                 const float* __restrict__ ew,
                                                 float* deg, int* cnt, unsigned char* __restrict__ rank,
                                                 const float* __restrict__ x, const float* __restrict__ pe,
                                                 const unsigned short* __restrict__ AT0,
                                                 unsigned short* __restrict__ oZ3, unsigned short* __restrict__ oZ2,
                                                 unsigned short* __restrict__ oZ1, unsigned short* __restrict__ oZ0,
                                                 int N, int E, int EPC) {
    __shared__ __align__(16) unsigned short As[64 * 168];
    const int bid = blockIdx.x;

    // phase 1: layer-0 pair GEMM tile (fused concat from f32 x|pe)
    {
        int P = bid & 1;
        int bx = bid >> 1;
        const unsigned short* Bta = AT0 + (size_t)(3 - 2 * P) * 128 * 160;
        const unsigned short* Btb = AT0 + (size_t)(2 - 2 * P) * 128 * 160;
        unsigned short* outA = (P == 0) ? oZ3 : oZ1;
        unsigned short* outB = (P == 0) ? oZ2 : oZ0;
        gemm_pair_regB<160, 1>(nullptr, x, pe, Bta, Btb, outA, outB, N, bx, As);
    }

    // phase 2: atomics after the last barrier — deg fire-and-forget; cnt returns rank (piggybacked)
    {
        int e0 = bid * EPC;
        int e1 = e0 + EPC;
        if (e1 > E) e1 = E;
        for (int e = e0 + threadIdx.x; e < e1; e += 256) {
            int s = src[e], d = dst[e];
            float w = (s == d) ? 0.f : ew[e];
            atomicAdd(&deg[s], w);
            rank[e] = (unsigned char)atomicAdd(&cnt[d], 1);
        }
    }
}

// ---------------- heads GEMM: BM=128, reg-B; [mu|logvar](f32) + bias ----------------

__global__ __launch_bounds__(256, 4) void k_gemm_heads(const unsigned short* __restrict__ Abf,
                                                       const unsigned short* __restrict__ Bt,
                                                       float* __restrict__ out,
                                                       const float* __restrict__ bmu, const float* __restrict__ blv,
                                                       int N) {
    constexpr int KPAD = 128;
    constexpr int LP = KPAD + 8;
    __shared__ __align__(16) unsigned short As[128 * LP];
    const int tid = threadIdx.x;
    const int row0 = blockIdx.x * 128;

    {
        constexpr int TOT = 128 * KPAD;
        for (int c = tid * 8; c < TOT; c += 256 * 8) {
            int r = c / KPAD;
            int k = c - r * KPAD;
            int gr = row0 + r;
            if (gr > N - 1) gr = N - 1;
            u16x8 v = *reinterpret_cast<const u16x8*>(&Abf[(size_t)gr * KPAD + k]);
            *reinterpret_cast<u16x8*>(&As[r * LP + k]) = v;
        }
    }
    __syncthreads();

    const int wave = tid >> 6, lane = tid & 63;
    const int lr = lane & 15, lg = lane >> 4;

    f32x4 acc[2][8];
#pragma unroll
    for (int i = 0; i < 2; i++)
#pragma unroll
        for (int j = 0; j < 8; j++) acc[i][j] = (f32x4){0.f, 0.f, 0.f, 0.f};

    asm volatile("s_nop 7"
                 : "+v"(acc[0][0]), "+v"(acc[0][4]), "+v"(acc[1][0]), "+v"(acc[1][4]));

#pragma unroll
    for (int ks = 0; ks < KPAD / 32; ks++) {
        u16x8 a0 = *reinterpret_cast<const u16x8*>(&As[(wave * 32 + lr) * LP + ks * 32 + lg * 8]);
        u16x8 a1 = *reinterpret_cast<const u16x8*>(&As[(wave * 32 + 16 + lr) * LP + ks * 32 + lg * 8]);
#pragma unroll
        for (int g = 0; g < 2; g++) {
            u16x8 b[4];
#pragma unroll
            for (int j = 0; j < 4; j++)
                b[j] = *reinterpret_cast<const u16x8*>(&Bt[(size_t)((g * 4 + j) * 16 + lr) * KPAD + ks * 32 + lg * 8]);
#pragma unroll
            for (int j = 0; j < 4; j++) {
                mfma16(acc[0][g * 4 + j], a0, b[j]);
                mfma16(acc[1][g * 4 + j], a1, b[j]);
            }
        }
    }

    asm volatile("s_nop 7\n\ts_nop 7\n\ts_nop 7"
                 : "+v"(acc[0][0]), "+v"(acc[0][4]), "+v"(acc[1][0]), "+v"(acc[1][4]));

#pragma unroll
    for (int fm = 0; fm < 2; fm++)
#pragma unroll
        for (int fn = 0; fn < 8; fn++)
#pragma unroll
            for (int i = 0; i < 4; i++) {
                int r = row0 + wave * 32 + fm * 16 + lg * 4 + i;
                if (r < N) {
                    int c = fn * 16 + lr;
                    if (c < 64) out[(size_t)r * 64 + c] = acc[fm][fn][i] + bmu[c];
                    else out[(size_t)N * 64 + (size_t)r * 64 + (c - 64)] = acc[fm][fn][i] + blv[c - 64];
                }
            }
}

// ---------------- sparse prop v2: half-wave split (2 rows/instr, 8 gathers in flight) ----------------
// lanes 0-31 handle even CSR slots, 32-63 odd; each lane loads uint2 (8B) = feats [4sl..4sl+3].

template <int MODE>  // 0: plain ; 1: + bias, relu
__global__ __launch_bounds__(256) void k_prop(const unsigned int* __restrict__ tin,
                                              const unsigned int* __restrict__ z,
                                              unsigned int* __restrict__ tout,
                                              const float* __restrict__ bias,
                                              const int* __restrict__ rowp,
                                              const long long* __restrict__ pack,
                                              int N, int E) {
    int wave = threadIdx.x >> 6, lane = threadIdx.x & 63;
    int node = blockIdx.x * 4 + wave;
    if (node >= N) return;
    int beg = rowp[node];
    int end = (node == N - 1) ? E : rowp[node + 1];
    const int half = lane >> 5, sl = lane & 31;
    float a0 = 0.f, a1 = 0.f, a2 = 0.f, a3 = 0.f;
    int e = beg + half;
    for (; e + 6 < end; e += 8) {
        long long q0 = __builtin_nontemporal_load(pack + e);
        long long q1 = __builtin_nontemporal_load(pack + e + 2);
        long long q2 = __builtin_nontemporal_load(pack + e + 4);
        long long q3 = __builtin_nontemporal_load(pack + e + 6);
        uint2 v0 = *reinterpret_cast<const uint2*>(&tin[(size_t)(unsigned int)q0 * 64 + sl * 2]);
        uint2 v1 = *reinterpret_cast<const uint2*>(&tin[(size_t)(unsigned int)q1 * 64 + sl * 2]);
        uint2 v2 = *reinterpret_cast<const uint2*>(&tin[(size_t)(unsigned int)q2 * 64 + sl * 2]);
        uint2 v3 = *reinterpret_cast<const uint2*>(&tin[(size_t)(unsigned int)q3 * 64 + sl * 2]);
        float w0 = __uint_as_float((unsigned int)((unsigned long long)q0 >> 32));
        float w1 = __uint_as_float((unsigned int)((unsigned long long)q1 >> 32));
        float w2 = __uint_as_float((unsigned int)((unsigned long long)q2 >> 32));
        float w3 = __uint_as_float((unsigned int)((unsigned long long)q3 >> 32));
        a0 = fmaf(w0, bflo(v0.x), a0); a1 = fmaf(w0, bfhi(v0.x), a1);
        a2 = fmaf(w0, bflo(v0.y), a2); a3 = fmaf(w0, bfhi(v0.y), a3);
        a0 = fmaf(w1, bflo(v1.x), a0); a1 = fmaf(w1, bfhi(v1.x), a1);
        a2 = fmaf(w1, bflo(v1.y), a2); a3 = fmaf(w1, bfhi(v1.y), a3);
        a0 = fmaf(w2, bflo(v2.x), a0); a1 = fmaf(w2, bfhi(v2.x), a1);
        a2 = fmaf(w2, bflo(v2.y), a2); a3 = fmaf(w2, bfhi(v2.y), a3);
        a0 = fmaf(w3, bflo(v3.x), a0); a1 = fmaf(w3, bfhi(v3.x), a1);
        a2 = fmaf(w3, bflo(v3.y), a2); a3 = fmaf(w3, bfhi(v3.y), a3);
    }
    for (; e < end; e += 2) {
        long long q0 = __builtin_nontemporal_load(pack + e);
        uint2 v0 = *reinterpret_cast<const uint2*>(&tin[(size_t)(unsigned int)q0 * 64 + sl * 2]);
        float w0 = __uint_as_float((unsigned int)((unsigned long long)q0 >> 32));
        a0 = fmaf(w0, bflo(v0.x), a0); a1 = fmaf(w0, bfhi(v0.x), a1);
        a2 = fmaf(w0, bflo(v0.y), a2); a3 = fmaf(w0, bfhi(v0.y), a3);
    }
    // cross-half reduce: lane l and l^32 hold the same feature slots
    a0 += __shfl_xor(a0, 32);
    a1 += __shfl_xor(a1, 32);
    a2 += __shfl_xor(a2, 32);
    a3 += __shfl_xor(a3, 32);
    if (lane < 32) {
        uint2 zv = *reinterpret_cast<const uint2*>(&z[(size_t)node * 64 + sl * 2]);
        float r0 = bflo(zv.x) + a0;
        float r1 = bfhi(zv.x) + a1;
        float r2 = bflo(zv.y) + a2;
        float r3 = bfhi(zv.y) + a3;
        if (MODE == 1) {
            r0 = fmaxf(r0 + bias[sl * 4 + 0], 0.f);
            r1 = fmaxf(r1 + bias[sl * 4 + 1], 0.f);
            r2 = fmaxf(r2 + bias[sl * 4 + 2], 0.f);
            r3 = fmaxf(r3 + bias[sl * 4 + 3], 0.f);
        }
        uint2 o;
        o.x = (unsigned int)f2bf(r0) | ((unsigned int)f2bf(r1) << 16);
        o.y = (unsigned int)f2bf(r2) | ((unsigned int)f2bf(r3) << 16);
        *reinterpret_cast<uint2*>(&tout[(size_t)node * 64 + sl * 2]) = o;
    }
}

// ---------------- launch ----------------

extern "C" void kernel_launch(void* const* d_in, const int* in_sizes, int n_in,
                              void* d_out, int out_size, void* d_ws, size_t ws_size,
                              hipStream_t stream) {
    const float* x   = (const float*)d_in[0];
    const int*   ei  = (const int*)d_in[1];
    const float* pe  = (const float*)d_in[2];
    const float* ew  = (const float*)d_in[3];
    const float* W0  = (const float*)d_in[4];
    const float* b0  = (const float*)d_in[5];
    const float* W1  = (const float*)d_in[6];
    const float* b1  = (const float*)d_in[7];
    const float* Wmu = (const float*)d_in[8];
    const float* bmu = (const float*)d_in[9];
    const float* Wlv = (const float*)d_in[10];
    const float* blv = (const float*)d_in[11];

    const int N = in_sizes[0] / 128;
    const int E = in_sizes[3];
    const int* src = ei;
    const int* dst = ei + E;

    char* ws = (char*)d_ws;
    size_t off = 0;
    auto alloc = [&](size_t bytes) {
        size_t o = off;
        off += (bytes + 1023) & ~(size_t)1023;
        return o;
    };
    float* deg = (float*)(ws + alloc(4 * (size_t)N));   // becomes dis in-place
    int* cnt   = (int*)(ws + alloc(4 * (size_t)N));
    size_t zero_bytes = off;                            // memset deg+cnt
    unsigned char* rank = (unsigned char*)(ws + alloc((size_t)E));
    int* rowp  = (int*)(ws + alloc(4 * (size_t)N));
    int* bsum  = (int*)(ws + alloc(4 * 128));
    unsigned short* AT0 = (unsigned short*)(ws + alloc(2 * 4 * 128 * 160));
    unsigned short* AT1 = (unsigned short*)(ws + alloc(2 * 4 * 128 * 128));
    unsigned short* ATH = (unsigned short*)(ws + alloc(2 * 128 * 128));
    int2* pack = (int2*)(ws + alloc(8 * (size_t)E));
    unsigned int* B1 = (unsigned int*)(ws + alloc(2 * (size_t)N * 128));
    unsigned int* B2 = (unsigned int*)(ws + alloc(2 * (size_t)N * 128));
    unsigned int* B3 = (unsigned int*)(ws + alloc(2 * (size_t)N * 128));
    unsigned int* B4 = (unsigned int*)(ws + alloc(2 * (size_t)N * 128));
    unsigned int* B5 = (unsigned int*)(ws + alloc(2 * (size_t)N * 128));

    hipMemsetAsync(ws, 0, zero_bytes, stream);

    dim3 b256(256);
    // weight prep (mega's gemm blocks read AT0)
    k_combine<<<dim3((4 * 128 * 160 + 255) / 256), b256, 0, stream>>>(W0, AT0, 144, 160);
    k_combine<<<dim3((4 * 128 * 128 + 255) / 256), b256, 0, stream>>>(W1, AT1, 128, 128);
    k_headsT<<<dim3((128 * 128 + 255) / 256), b256, 0, stream>>>(Wmu, Wlv, ATH);

    // K1: every block = layer-0 pair-GEMM tile (fused concat), then tail atomics (deg FF, cnt->rank)
    int G64 = (N + 63) / 64;
    int total = 2 * G64;
    int EPC = (E + total - 1) / total;
    k_mega<<<dim3(total), b256, 0, stream>>>(src, dst, ew, deg, cnt, rank, x, pe, AT0,
                                             (unsigned short*)B1, (unsigned short*)B2,
                                             (unsigned short*)B3, (unsigned short*)B4,
                                             N, E, EPC);

    k_dis<<<dim3((N + 255) / 256), b256, 0, stream>>>(deg, N);
    int nb = (N + 1023) / 1024;
    k_blocksum<<<dim3(nb), dim3(1024), 0, stream>>>(cnt, bsum, N);
    k_scan_bsum<<<dim3(1), dim3(128), 0, stream>>>(bsum, nb);
    k_scan<<<dim3(nb), dim3(1024), 0, stream>>>(cnt, bsum, rowp, N);
    k_build_csr<<<dim3((E + 511) / 512), b256, 0, stream>>>(src, dst, ew, deg, rowp, rank, pack, E);

    dim3 gg(G64, 2);
    dim3 gh((N + 127) / 128);
    dim3 gp((N + 3) / 4);
    const long long* packll = (const long long*)pack;

    // layer 0 (Horner): B1=Z3 B2=Z2 B3=Z1 B4=Z0 (from K1)
    k_prop<0><<<gp, b256, 0, stream>>>(B1, B2, B5, nullptr, rowp, packll, N, E);   // B5 = Z2 + P Z3
    k_prop<0><<<gp, b256, 0, stream>>>(B5, B3, B1, nullptr, rowp, packll, N, E);   // B1 = Z1 + P B5
    k_prop<1><<<gp, b256, 0, stream>>>(B1, B4, B2, b0, rowp, packll, N, E);        // B2 = h1

    // layer 1: both pairs in one launch
    const unsigned short* h1 = (const unsigned short*)B2;
    k_gemm_pair128<<<gg, b256, 0, stream>>>(h1, AT1,
                                            (unsigned short*)B3, (unsigned short*)B4,
                                            (unsigned short*)B1, (unsigned short*)B5, N);
    k_prop<0><<<gp, b256, 0, stream>>>(B3, B4, B2, nullptr, rowp, packll, N, E);   // B2 = Z2' + P Z3'
    k_prop<0><<<gp, b256, 0, stream>>>(B2, B1, B3, nullptr, rowp, packll, N, E);   // B3 = Z1' + P B2
    k_prop<1><<<gp, b256, 0, stream>>>(B3, B5, B4, b1, rowp, packll, N, E);        // B4 = h2

    // heads
    k_gemm_heads<<<gh, b256, 0, stream>>>((const unsigned short*)B4, ATH, (float*)d_out, bmu, blv, N);
}

// Round 8
// 766.240 us; speedup vs baseline: 1.2257x; 1.0994x over previous
//
#include <hip/hip_runtime.h>
#include <hip/hip_bf16.h>

typedef float f32x4 __attribute__((ext_vector_type(4)));
typedef unsigned short u16x8 __attribute__((ext_vector_type(8)));

static __device__ __forceinline__ void mfma16(f32x4& c, const u16x8& a, const u16x8& b) {
    asm("v_mfma_f32_16x16x32_bf16 %0, %1, %2, %0" : "+v"(c) : "v"(a), "v"(b));
}

static __device__ __forceinline__ unsigned short f2bf(float f) {
    __hip_bfloat16 h = __float2bfloat16(f);
    return *reinterpret_cast<unsigned short*>(&h);
}

static __device__ __forceinline__ float bflo(unsigned int v) { return __uint_as_float(v << 16); }
static __device__ __forceinline__ float bfhi(unsigned int v) { return __uint_as_float(v & 0xffff0000u); }

// ---------------- small prep kernels ----------------

// fused: deg -> rsqrt (dis) elementwise, plus block-level sum of cnt
__global__ __launch_bounds__(1024) void k_dis_blocksum(float* deg, const int* __restrict__ cnt,
                                                       int* bsum, int N) {
    __shared__ int sd[1024];
    int i = blockIdx.x * 1024 + threadIdx.x;
    if (i < N) {
        float d = deg[i];
        deg[i] = (d > 0.f) ? rsqrtf(d) : 0.f;
    }
    sd[threadIdx.x] = (i < N) ? cnt[i] : 0;
    __syncthreads();
    for (int s = 512; s > 0; s >>= 1) {
        if (threadIdx.x < s) sd[threadIdx.x] += sd[threadIdx.x + s];
        __syncthreads();
    }
    if (threadIdx.x == 0) bsum[blockIdx.x] = sd[0];
}

__global__ __launch_bounds__(128) void k_scan_bsum(int* bsum, int nb) {
    __shared__ int sd[128];
    int t = threadIdx.x;
    int v = (t < nb) ? bsum[t] : 0;
    sd[t] = v;
    __syncthreads();
    for (int d = 1; d < 128; d <<= 1) {
        int x = (t >= d) ? sd[t - d] : 0;
        __syncthreads();
        sd[t] += x;
        __syncthreads();
    }
    if (t < nb) bsum[t] = sd[t] - v;  // exclusive block offsets
}

__global__ __launch_bounds__(1024) void k_scan(const int* __restrict__ cnt, const int* __restrict__ bsum,
                                               int* rowp, int N) {
    __shared__ int sd[1024];
    int i = blockIdx.x * 1024 + threadIdx.x;
    int v = (i < N) ? cnt[i] : 0;
    sd[threadIdx.x] = v;
    __syncthreads();
    for (int d = 1; d < 1024; d <<= 1) {
        int x = (threadIdx.x >= d) ? sd[threadIdx.x - d] : 0;
        __syncthreads();
        sd[threadIdx.x] += x;
        __syncthreads();
    }
    if (i < N) rowp[i] = sd[threadIdx.x] - v + bsum[blockIdx.x];
}

// atomic-free CSR fill: pos = rowp[dst] + rank (u8, captured during mega's counting atomics)
__global__ __launch_bounds__(256) void k_build_csr(const int* __restrict__ src, const int* __restrict__ dst,
                                                   const float* __restrict__ ew, const float* __restrict__ dis,
                                                   const int* __restrict__ rowp,
                                                   const unsigned char* __restrict__ rank,
                                                   int2* __restrict__ pack, int E) {
    int base = blockIdx.x * 512 + threadIdx.x;
#pragma unroll
    for (int u = 0; u < 2; u++) {
        int e = base + u * 256;
        if (e < E) {
            int s = src[e], d = dst[e];
            float w = (s == d) ? 0.f : ew[e];
            float wh = -dis[s] * w * dis[d];
            int pos = rowp[d] + (int)rank[e];
            int2 p;
            p.x = s;
            p.y = __float_as_int(wh);
            pack[pos] = p;
        }
    }
}

// ---------------- weight prep ----------------

// AT[sel][n][kk] = A_sel[kk][n] (transposed, bf16), A0=W0-W2, A1=W1-3W3, A2=2W2, A3=4W3
__global__ __launch_bounds__(256) void k_combine(const float* __restrict__ W, unsigned short* __restrict__ AT,
                                                 int D, int KPAD) {
    int i = blockIdx.x * 256 + threadIdx.x;
    int tot = 4 * 128 * KPAD;
    if (i >= tot) return;
    int sel = i / (128 * KPAD);
    int rem = i - sel * 128 * KPAD;
    int n = rem / KPAD;
    int kk = rem - n * KPAD;
    float v = 0.f;
    if (kk < D) {
        if (sel == 0)      v = W[(0 * D + kk) * 128 + n] - W[(2 * D + kk) * 128 + n];
        else if (sel == 1) v = W[(1 * D + kk) * 128 + n] - 3.f * W[(3 * D + kk) * 128 + n];
        else if (sel == 2) v = 2.f * W[(2 * D + kk) * 128 + n];
        else               v = 4.f * W[(3 * D + kk) * 128 + n];
    }
    AT[i] = f2bf(v);
}

__global__ __launch_bounds__(256) void k_headsT(const float* __restrict__ Wmu, const float* __restrict__ Wlv,
                                                unsigned short* __restrict__ AT) {
    int i = blockIdx.x * 256 + threadIdx.x;
    if (i >= 128 * 128) return;
    int n = i >> 7, kk = i & 127;
    float v = (n < 64) ? Wmu[kk * 64 + n] : Wlv[kk * 64 + (n - 64)];
    AT[i] = f2bf(v);
}

// ---------------- reg-B pair GEMM body: BM=64, BN=128 (all cols), 2 weights/block ----------------

template <int KPAD, int SRC>
static __device__ __forceinline__ void gemm_pair_regB(const unsigned short* __restrict__ Abf,
                                                      const float* __restrict__ x,
                                                      const float* __restrict__ pe,
                                                      const unsigned short* __restrict__ Bta,
                                                      const unsigned short* __restrict__ Btb,
                                                      unsigned short* __restrict__ outA,
                                                      unsigned short* __restrict__ outB,
                                                      int N, int bx, unsigned short* As) {
    constexpr int LP = KPAD + 8;
    const int tid = threadIdx.x;
    const int row0 = bx * 64;

    {   // stage A tile (64 x KPAD)
        constexpr int TOT = 64 * KPAD;
        for (int c = tid * 8; c < TOT; c += 256 * 8) {
            int r = c / KPAD;
            int k = c - r * KPAD;
            int gr = row0 + r;
            if (gr > N - 1) gr = N - 1;
            u16x8 v;
            if (SRC == 0) {
                v = *reinterpret_cast<const u16x8*>(&Abf[(size_t)gr * KPAD + k]);
            } else {
                if (k < 128) {
                    float4 f0 = *reinterpret_cast<const float4*>(&x[(size_t)gr * 128 + k]);
                    float4 f1 = *reinterpret_cast<const float4*>(&x[(size_t)gr * 128 + k + 4]);
                    v[0] = f2bf(f0.x); v[1] = f2bf(f0.y); v[2] = f2bf(f0.z); v[3] = f2bf(f0.w);
                    v[4] = f2bf(f1.x); v[5] = f2bf(f1.y); v[6] = f2bf(f1.z); v[7] = f2bf(f1.w);
                } else if (k < 144) {
                    float4 f0 = *reinterpret_cast<const float4*>(&pe[(size_t)gr * 16 + (k - 128)]);
                    float4 f1 = *reinterpret_cast<const float4*>(&pe[(size_t)gr * 16 + (k - 124)]);
                    v[0] = f2bf(f0.x); v[1] = f2bf(f0.y); v[2] = f2bf(f0.z); v[3] = f2bf(f0.w);
                    v[4] = f2bf(f1.x); v[5] = f2bf(f1.y); v[6] = f2bf(f1.z); v[7] = f2bf(f1.w);
                } else {
                    v = (u16x8){0, 0, 0, 0, 0, 0, 0, 0};
                }
            }
            *reinterpret_cast<u16x8*>(&As[r * LP + k]) = v;
        }
    }
    __syncthreads();

    const int wave = tid >> 6, lane = tid & 63;
    const int wm = wave & 1, ww = wave >> 1;
    const int lr = lane & 15, lg = lane >> 4;
    const unsigned short* Bw = ww ? Btb : Bta;

    f32x4 acc[2][8];
#pragma unroll
    for (int i = 0; i < 2; i++)
#pragma unroll
        for (int j = 0; j < 8; j++) acc[i][j] = (f32x4){0.f, 0.f, 0.f, 0.f};

    asm volatile("s_nop 7"
                 : "+v"(acc[0][0]), "+v"(acc[0][4]), "+v"(acc[1][0]), "+v"(acc[1][4]));

    constexpr int KS = KPAD / 32;
#pragma unroll
    for (int ks = 0; ks < KS; ks++) {
        u16x8 a0 = *reinterpret_cast<const u16x8*>(&As[(wm * 32 + lr) * LP + ks * 32 + lg * 8]);
        u16x8 a1 = *reinterpret_cast<const u16x8*>(&As[(wm * 32 + 16 + lr) * LP + ks * 32 + lg * 8]);
#pragma unroll
        for (int g = 0; g < 2; g++) {
            u16x8 b[4];
#pragma unroll
            for (int j = 0; j < 4; j++)
                b[j] = *reinterpret_cast<const u16x8*>(&Bw[(size_t)((g * 4 + j) * 16 + lr) * KPAD + ks * 32 + lg * 8]);
#pragma unroll
            for (int j = 0; j < 4; j++) {
                mfma16(acc[0][g * 4 + j], a0, b[j]);
                mfma16(acc[1][g * 4 + j], a1, b[j]);
            }
        }
    }

    asm volatile("s_nop 7\n\ts_nop 7\n\ts_nop 7"
                 : "+v"(acc[0][0]), "+v"(acc[0][4]), "+v"(acc[1][0]), "+v"(acc[1][4]));

    unsigned short* outp = ww ? outB : outA;
#pragma unroll
    for (int fm = 0; fm < 2; fm++)
#pragma unroll
        for (int fn = 0; fn < 8; fn++)
#pragma unroll
            for (int i = 0; i < 4; i++) {
                int r = row0 + wm * 32 + fm * 16 + lg * 4 + i;
                if (r < N) outp[(size_t)r * 128 + fn * 16 + lr] = f2bf(acc[fm][fn][i]);
            }
}

// layer-1: grid = (G64, 2); y picks pair P.
__global__ __launch_bounds__(256, 4) void k_gemm_pair128(const unsigned short* __restrict__ Abf,
                                                         const unsigned short* __restrict__ AT1,
                                                         unsigned short* __restrict__ oZ3,
                                                         unsigned short* __restrict__ oZ2,
                                                         unsigned short* __restrict__ oZ1,
                                                         unsigned short* __restrict__ oZ0,
                                                         int N) {
    __shared__ __align__(16) unsigned short As[64 * 136];
    const int P = blockIdx.y;
    const unsigned short* Bta = AT1 + (size_t)(3 - 2 * P) * 128 * 128;
    const unsigned short* Btb = AT1 + (size_t)(2 - 2 * P) * 128 * 128;
    unsigned short* outA = (P == 0) ? oZ3 : oZ1;
    unsigned short* outB = (P == 0) ? oZ2 : oZ0;
    gemm_pair_regB<128, 0>(Abf, nullptr, nullptr, Bta, Btb, outA, outB, N, blockIdx.x, As);
}

// ---------------- K1 mega: {layer-0 pair-GEMM tile} then {deg fire-and-forget + cnt/rank atomics} ----------------

__global__ __launch_bounds__(256, 4) void k_mega(const int* __restrict__ src, const int* __restrict__ dst,
                                                 const float* __restrict__ ew,
                                                 float* deg, int* cnt, unsigned char* __restrict__ rank,
                                                 const float* __restrict__ x, const float* __restrict__ pe,
                                                 const unsigned short* __restrict__ AT0,
                                                 unsigned short* __restrict__ oZ3, unsigned short* __restrict__ oZ2,
                                                 unsigned short* __restrict__ oZ1, unsigned short* __restrict__ oZ0,
                                                 int N, int E, int EPC) {
    __shared__ __align__(16) unsigned short As[64 * 168];
    const int bid = blockIdx.x;

    // phase 1: layer-0 pair GEMM tile (fused concat from f32 x|pe)
    {
        int P = bid & 1;
        int bx = bid >> 1;
        const unsigned short* Bta = AT0 + (size_t)(3 - 2 * P) * 128 * 160;
        const unsigned short* Btb = AT0 + (size_t)(2 - 2 * P) * 128 * 160;
        unsigned short* outA = (P == 0) ? oZ3 : oZ1;
        unsigned short* outB = (P == 0) ? oZ2 : oZ0;
        gemm_pair_regB<160, 1>(nullptr, x, pe, Bta, Btb, outA, outB, N, bx, As);
    }

    // phase 2: atomics after the last barrier — deg fire-and-forget; cnt returns rank (piggybacked)
    {
        int e0 = bid * EPC;
        int e1 = e0 + EPC;
        if (e1 > E) e1 = E;
        for (int e = e0 + threadIdx.x; e < e1; e += 256) {
            int s = src[e], d = dst[e];
            float w = (s == d) ? 0.f : ew[e];
            atomicAdd(&deg[s], w);
            rank[e] = (unsigned char)atomicAdd(&cnt[d], 1);
        }
    }
}

// ---------------- heads GEMM: BM=128, reg-B; [mu|logvar](f32) + bias ----------------

__global__ __launch_bounds__(256, 4) void k_gemm_heads(const unsigned short* __restrict__ Abf,
                                                       const unsigned short* __restrict__ Bt,
                                                       float* __restrict__ out,
                                                       const float* __restrict__ bmu, const float* __restrict__ blv,
                                                       int N) {
    constexpr int KPAD = 128;
    constexpr int LP = KPAD + 8;
    __shared__ __align__(16) unsigned short As[128 * LP];
    const int tid = threadIdx.x;
    const int row0 = blockIdx.x * 128;

    {
        constexpr int TOT = 128 * KPAD;
        for (int c = tid * 8; c < TOT; c += 256 * 8) {
            int r = c / KPAD;
            int k = c - r * KPAD;
            int gr = row0 + r;
            if (gr > N - 1) gr = N - 1;
            u16x8 v = *reinterpret_cast<const u16x8*>(&Abf[(size_t)gr * KPAD + k]);
            *reinterpret_cast<u16x8*>(&As[r * LP + k]) = v;
        }
    }
    __syncthreads();

    const int wave = tid >> 6, lane = tid & 63;
    const int lr = lane & 15, lg = lane >> 4;

    f32x4 acc[2][8];
#pragma unroll
    for (int i = 0; i < 2; i++)
#pragma unroll
        for (int j = 0; j < 8; j++) acc[i][j] = (f32x4){0.f, 0.f, 0.f, 0.f};

    asm volatile("s_nop 7"
                 : "+v"(acc[0][0]), "+v"(acc[0][4]), "+v"(acc[1][0]), "+v"(acc[1][4]));

#pragma unroll
    for (int ks = 0; ks < KPAD / 32; ks++) {
        u16x8 a0 = *reinterpret_cast<const u16x8*>(&As[(wave * 32 + lr) * LP + ks * 32 + lg * 8]);
        u16x8 a1 = *reinterpret_cast<const u16x8*>(&As[(wave * 32 + 16 + lr) * LP + ks * 32 + lg * 8]);
#pragma unroll
        for (int g = 0; g < 2; g++) {
            u16x8 b[4];
#pragma unroll
            for (int j = 0; j < 4; j++)
                b[j] = *reinterpret_cast<const u16x8*>(&Bt[(size_t)((g * 4 + j) * 16 + lr) * KPAD + ks * 32 + lg * 8]);
#pragma unroll
            for (int j = 0; j < 4; j++) {
                mfma16(acc[0][g * 4 + j], a0, b[j]);
                mfma16(acc[1][g * 4 + j], a1, b[j]);
            }
        }
    }

    asm volatile("s_nop 7\n\ts_nop 7\n\ts_nop 7"
                 : "+v"(acc[0][0]), "+v"(acc[0][4]), "+v"(acc[1][0]), "+v"(acc[1][4]));

#pragma unroll
    for (int fm = 0; fm < 2; fm++)
#pragma unroll
        for (int fn = 0; fn < 8; fn++)
#pragma unroll
            for (int i = 0; i < 4; i++) {
                int r = row0 + wave * 32 + fm * 16 + lg * 4 + i;
                if (r < N) {
                    int c = fn * 16 + lr;
                    if (c < 64) out[(size_t)r * 64 + c] = acc[fm][fn][i] + bmu[c];
                    else out[(size_t)N * 64 + (size_t)r * 64 + (c - 64)] = acc[fm][fn][i] + blv[c - 64];
                }
            }
}

// ---------------- sparse prop v3: quarter-wave split (4 rows/instr, 8 rows in flight) ----------------
// 4 groups of 16 lanes; group g handles CSR slots e = beg+g, +4, ... ; lane loads uint4 (16B)
// so 16 lanes cover one full 256B row. Cross-group reduce: shfl_xor 16, 32.

template <int MODE>  // 0: plain ; 1: + bias, relu
__global__ __launch_bounds__(256) void k_prop(const uint4* __restrict__ tin4,
                                              const uint4* __restrict__ z4,
                                              uint4* __restrict__ tout4,
                                              const float* __restrict__ bias,
                                              const int* __restrict__ rowp,
                                              const long long* __restrict__ pack,
                                              int N, int E) {
    int wave = threadIdx.x >> 6, lane = threadIdx.x & 63;
    int node = blockIdx.x * 4 + wave;
    if (node >= N) return;
    int beg = rowp[node];
    int end = (node == N - 1) ? E : rowp[node + 1];
    const int grp = lane >> 4, li = lane & 15;
    float s0 = 0.f, s1 = 0.f, s2 = 0.f, s3 = 0.f, s4 = 0.f, s5 = 0.f, s6 = 0.f, s7 = 0.f;
    int e = beg + grp;
    for (; e + 4 < end; e += 8) {
        long long qa = __builtin_nontemporal_load(pack + e);
        long long qb = __builtin_nontemporal_load(pack + e + 4);
        uint4 va = tin4[(size_t)(unsigned int)qa * 16 + li];
        uint4 vb = tin4[(size_t)(unsigned int)qb * 16 + li];
        float wa = __uint_as_float((unsigned int)((unsigned long long)qa >> 32));
        float wb = __uint_as_float((unsigned int)((unsigned long long)qb >> 32));
        s0 = fmaf(wa, bflo(va.x), s0); s1 = fmaf(wa, bfhi(va.x), s1);
        s2 = fmaf(wa, bflo(va.y), s2); s3 = fmaf(wa, bfhi(va.y), s3);
        s4 = fmaf(wa, bflo(va.z), s4); s5 = fmaf(wa, bfhi(va.z), s5);
        s6 = fmaf(wa, bflo(va.w), s6); s7 = fmaf(wa, bfhi(va.w), s7);
        s0 = fmaf(wb, bflo(vb.x), s0); s1 = fmaf(wb, bfhi(vb.x), s1);
        s2 = fmaf(wb, bflo(vb.y), s2); s3 = fmaf(wb, bfhi(vb.y), s3);
        s4 = fmaf(wb, bflo(vb.z), s4); s5 = fmaf(wb, bfhi(vb.z), s5);
        s6 = fmaf(wb, bflo(vb.w), s6); s7 = fmaf(wb, bfhi(vb.w), s7);
    }
    for (; e < end; e += 4) {
        long long qa = __builtin_nontemporal_load(pack + e);
        uint4 va = tin4[(size_t)(unsigned int)qa * 16 + li];
        float wa = __uint_as_float((unsigned int)((unsigned long long)qa >> 32));
        s0 = fmaf(wa, bflo(va.x), s0); s1 = fmaf(wa, bfhi(va.x), s1);
        s2 = fmaf(wa, bflo(va.y), s2); s3 = fmaf(wa, bfhi(va.y), s3);
        s4 = fmaf(wa, bflo(va.z), s4); s5 = fmaf(wa, bfhi(va.z), s5);
        s6 = fmaf(wa, bflo(va.w), s6); s7 = fmaf(wa, bfhi(va.w), s7);
    }
    // reduce across the 4 groups (lanes with equal li)
    s0 += __shfl_xor(s0, 16); s1 += __shfl_xor(s1, 16);
    s2 += __shfl_xor(s2, 16); s3 += __shfl_xor(s3, 16);
    s4 += __shfl_xor(s4, 16); s5 += __shfl_xor(s5, 16);
    s6 += __shfl_xor(s6, 16); s7 += __shfl_xor(s7, 16);
    s0 += __shfl_xor(s0, 32); s1 += __shfl_xor(s1, 32);
    s2 += __shfl_xor(s2, 32); s3 += __shfl_xor(s3, 32);
    s4 += __shfl_xor(s4, 32); s5 += __shfl_xor(s5, 32);
    s6 += __shfl_xor(s6, 32); s7 += __shfl_xor(s7, 32);
    if (lane < 16) {
        uint4 zv = z4[(size_t)node * 16 + li];
        float r0 = bflo(zv.x) + s0, r1 = bfhi(zv.x) + s1;
        float r2 = bflo(zv.y) + s2, r3 = bfhi(zv.y) + s3;
        float r4 = bflo(zv.z) + s4, r5 = bfhi(zv.z) + s5;
        float r6 = bflo(zv.w) + s6, r7 = bfhi(zv.w) + s7;
        if (MODE == 1) {
            const float* bp = bias + li * 8;
            r0 = fmaxf(r0 + bp[0], 0.f); r1 = fmaxf(r1 + bp[1], 0.f);
            r2 = fmaxf(r2 + bp[2], 0.f); r3 = fmaxf(r3 + bp[3], 0.f);
            r4 = fmaxf(r4 + bp[4], 0.f); r5 = fmaxf(r5 + bp[5], 0.f);
            r6 = fmaxf(r6 + bp[6], 0.f); r7 = fmaxf(r7 + bp[7], 0.f);
        }
        uint4 o;
        o.x = (unsigned int)f2bf(r0) | ((unsigned int)f2bf(r1) << 16);
        o.y = (unsigned int)f2bf(r2) | ((unsigned int)f2bf(r3) << 16);
        o.z = (unsigned int)f2bf(r4) | ((unsigned int)f2bf(r5) << 16);
        o.w = (unsigned int)f2bf(r6) | ((unsigned int)f2bf(r7) << 16);
        tout4[(size_t)node * 16 + li] = o;
    }
}

// ---------------- launch ----------------

extern "C" void kernel_launch(void* const* d_in, const int* in_sizes, int n_in,
                              void* d_out, int out_size, void* d_ws, size_t ws_size,
                              hipStream_t stream) {
    const float* x   = (const float*)d_in[0];
    const int*   ei  = (const int*)d_in[1];
    const float* pe  = (const float*)d_in[2];
    const float* ew  = (const float*)d_in[3];
    const float* W0  = (const float*)d_in[4];
    const float* b0  = (const float*)d_in[5];
    const float* W1  = (const float*)d_in[6];
    const float* b1  = (const float*)d_in[7];
    const float* Wmu = (const float*)d_in[8];
    const float* bmu = (const float*)d_in[9];
    const float* Wlv = (const float*)d_in[10];
    const float* blv = (const float*)d_in[11];

    const int N = in_sizes[0] / 128;
    const int E = in_sizes[3];
    const int* src = ei;
    const int* dst = ei + E;

    char* ws = (char*)d_ws;
    size_t off = 0;
    auto alloc = [&](size_t bytes) {
        size_t o = off;
        off += (bytes + 1023) & ~(size_t)1023;
        return o;
    };
    float* deg = (float*)(ws + alloc(4 * (size_t)N));   // becomes dis in-place
    int* cnt   = (int*)(ws + alloc(4 * (size_t)N));
    size_t zero_bytes = off;                            // memset deg+cnt
    unsigned char* rank = (unsigned char*)(ws + alloc((size_t)E));
    int* rowp  = (int*)(ws + alloc(4 * (size_t)N));
    int* bsum  = (int*)(ws + alloc(4 * 128));
    unsigned short* AT0 = (unsigned short*)(ws + alloc(2 * 4 * 128 * 160));
    unsigned short* AT1 = (unsigned short*)(ws + alloc(2 * 4 * 128 * 128));
    unsigned short* ATH = (unsigned short*)(ws + alloc(2 * 128 * 128));
    int2* pack = (int2*)(ws + alloc(8 * (size_t)E));
    unsigned int* B1 = (unsigned int*)(ws + alloc(2 * (size_t)N * 128));
    unsigned int* B2 = (unsigned int*)(ws + alloc(2 * (size_t)N * 128));
    unsigned int* B3 = (unsigned int*)(ws + alloc(2 * (size_t)N * 128));
    unsigned int* B4 = (unsigned int*)(ws + alloc(2 * (size_t)N * 128));
    unsigned int* B5 = (unsigned int*)(ws + alloc(2 * (size_t)N * 128));

    hipMemsetAsync(ws, 0, zero_bytes, stream);

    dim3 b256(256);
    // weight prep (mega's gemm blocks read AT0)
    k_combine<<<dim3((4 * 128 * 160 + 255) / 256), b256, 0, stream>>>(W0, AT0, 144, 160);
    k_combine<<<dim3((4 * 128 * 128 + 255) / 256), b256, 0, stream>>>(W1, AT1, 128, 128);
    k_headsT<<<dim3((128 * 128 + 255) / 256), b256, 0, stream>>>(Wmu, Wlv, ATH);

    // K1: every block = layer-0 pair-GEMM tile (fused concat), then tail atomics (deg FF, cnt->rank)
    int G64 = (N + 63) / 64;
    int total = 2 * G64;
    int EPC = (E + total - 1) / total;
    k_mega<<<dim3(total), b256, 0, stream>>>(src, dst, ew, deg, cnt, rank, x, pe, AT0,
                                             (unsigned short*)B1, (unsigned short*)B2,
                                             (unsigned short*)B3, (unsigned short*)B4,
                                             N, E, EPC);

    int nb = (N + 1023) / 1024;
    k_dis_blocksum<<<dim3(nb), dim3(1024), 0, stream>>>(deg, cnt, bsum, N);
    k_scan_bsum<<<dim3(1), dim3(128), 0, stream>>>(bsum, nb);
    k_scan<<<dim3(nb), dim3(1024), 0, stream>>>(cnt, bsum, rowp, N);
    k_build_csr<<<dim3((E + 511) / 512), b256, 0, stream>>>(src, dst, ew, deg, rowp, rank, pack, E);

    dim3 gg(G64, 2);
    dim3 gh((N + 127) / 128);
    dim3 gp((N + 3) / 4);
    const long long* packll = (const long long*)pack;
    uint4* B1v = (uint4*)B1; uint4* B2v = (uint4*)B2; uint4* B3v = (uint4*)B3;
    uint4* B4v = (uint4*)B4; uint4* B5v = (uint4*)B5;

    // layer 0 (Horner): B1=Z3 B2=Z2 B3=Z1 B4=Z0 (from K1)
    k_prop<0><<<gp, b256, 0, stream>>>(B1v, B2v, B5v, nullptr, rowp, packll, N, E);   // B5 = Z2 + P Z3
    k_prop<0><<<gp, b256, 0, stream>>>(B5v, B3v, B1v, nullptr, rowp, packll, N, E);   // B1 = Z1 + P B5
    k_prop<1><<<gp, b256, 0, stream>>>(B1v, B4v, B2v, b0, rowp, packll, N, E);        // B2 = h1

    // layer 1: both pairs in one launch
    const unsigned short* h1 = (const unsigned short*)B2;
    k_gemm_pair128<<<gg, b256, 0, stream>>>(h1, AT1,
                                            (unsigned short*)B3, (unsigned short*)B4,
                                            (unsigned short*)B1, (unsigned short*)B5, N);
    k_prop<0><<<gp, b256, 0, stream>>>(B3v, B4v, B2v, nullptr, rowp, packll, N, E);   // B2 = Z2' + P Z3'
    k_prop<0><<<gp, b256, 0, stream>>>(B2v, B1v, B3v, nullptr, rowp, packll, N, E);   // B3 = Z1' + P B2
    k_prop<1><<<gp, b256, 0, stream>>>(B3v, B5v, B4v, b1, rowp, packll, N, E);        // B4 = h2

    // heads
    k_gemm_heads<<<gh, b256, 0, stream>>>((const unsigned short*)B4, ATH, (float*)d_out, bmu, blv, N);
}